// Round 6
// baseline (1130.966 us; speedup 1.0000x reference)
//
#include <hip/hip_runtime.h>
#include <math.h>

#define BB 32
#define CC 3
#define HH 224
#define WW 224
#define HWS (HH*WW)            // 50176
#define NELEM (BB*CC*HWS)      // 4,816,896
#define NTAPS (9*HWS)          // 451,584
#define EPS_IN 1e-5f
#define LNUM 10

#define NBLK_CONV (HWS/32)     // 1568 blocks, 32 pixels each, all 32 batches
#define PIX_PER_XCD (HWS/8)    // 6272
#define NBLK_NORM (NELEM/4/256) // 4704 = 8 * 588

__device__ __forceinline__ float fast_tanh(float z) {
    z = fminf(fmaxf(z, -15.f), 15.f);
    float e = __expf(2.f * z);
    return (e - 1.f) * __frcp_rn(e + 1.f);
}

// ---------------- zero stats ----------------
__global__ void zero_kernel(float* __restrict__ p, int n) {
    int i = blockIdx.x * 256 + threadIdx.x;
    if (i < n) p[i] = 0.f;
}

// ------- precompute expanded taps: clamped flat idx + masked weights ------
__global__ __launch_bounds__(256) void taps_kernel(
    const float* __restrict__ off,   // [18,H,W] batch-0 offset plane
    int4* __restrict__ ti, float4* __restrict__ tw)
{
    int gid = blockIdx.x * 256 + threadIdx.x;    // k*HWS + pix, grid exact
    int k = gid / HWS, pix = gid - k * HWS;
    int h = pix / WW, wc = pix - h * WW;
    int ky = k / 3, kx = k - 3 * ky;
    float dy = off[(2 * k)     * HWS + pix];
    float dx = off[(2 * k + 1) * HWS + pix];
    float py = (float)(h  + ky - 1) + dy;
    float px = (float)(wc + kx - 1) + dx;
    float y0f = floorf(py), x0f = floorf(px);
    float wy = py - y0f, wx = px - x0f;
    int iy0 = (int)y0f, ix0 = (int)x0f;
    int iy1 = iy0 + 1,  ix1 = ix0 + 1;
    float vy0 = (iy0 >= 0 && iy0 < HH) ? 1.f : 0.f;
    float vy1 = (iy1 >= 0 && iy1 < HH) ? 1.f : 0.f;
    float vx0 = (ix0 >= 0 && ix0 < WW) ? 1.f : 0.f;
    float vx1 = (ix1 >= 0 && ix1 < WW) ? 1.f : 0.f;
    int cy0 = min(max(iy0, 0), HH - 1), cy1 = min(max(iy1, 0), HH - 1);
    int cx0 = min(max(ix0, 0), WW - 1), cx1 = min(max(ix1, 0), WW - 1);
    int4 ii;
    ii.x = cy0 * WW + cx0; ii.y = cy0 * WW + cx1;
    ii.z = cy1 * WW + cx0; ii.w = cy1 * WW + cx1;
    float4 ww;
    ww.x = (1.f - wy) * (1.f - wx) * vy0 * vx0;
    ww.y = (1.f - wy) * wx         * vy0 * vx1;
    ww.z = wy         * (1.f - wx) * vy1 * vx0;
    ww.w = wy         * wx         * vy1 * vx1;
    ti[gid] = ii; tw[gid] = ww;
}

// ---------------- transpose [B,C,H,W] -> [C,HW,B] ----------------
__global__ __launch_bounds__(256) void transpose_in_kernel(
    const float* __restrict__ x, float* __restrict__ xT)
{
    __shared__ float tile[64][33];
    int bid = blockIdx.x;
    int c = bid / (HWS / 64);
    int pix0 = (bid % (HWS / 64)) * 64;
    int t = threadIdx.x;
    int i = t & 63, brow = t >> 6;
    #pragma unroll
    for (int jj = 0; jj < 8; ++jj) {
        int b = brow + jj * 4;
        tile[i][b] = x[((size_t)(b * 3 + c)) * HWS + pix0 + i];
    }
    __syncthreads();
    int b2 = t & 31, irow = t >> 5;
    #pragma unroll
    for (int j = 0; j < 8; ++j) {
        int i2 = irow + j * 8;
        xT[((size_t)(c * HWS + pix0 + i2)) * 32 + b2] = tile[i2][b2];
    }
}

// ---------------- deformable conv in [C,HW,B] layout + stats ----------------
// thread = (pixel, batch-quad). 8 lanes share a pixel; each handles 4 batch
// elements via float4 gathers — every gather instruction reads 8 x 128B fully
// utilized contiguous segments (minimum L1 line-touches). XCD-contiguous
// block swizzle keeps each XCD's x-slice (2.4MB) + tap slice in its L2.
__global__ __launch_bounds__(256) void conv_t_kernel(
    const float* __restrict__ xT,    // [C,HW,B]
    const int4*  __restrict__ ti,    // [9,HW] gather indices
    const float4* __restrict__ tw,   // [9,HW] bilinear weights
    const float* __restrict__ wt,    // [3,3,9] conv weights
    float* __restrict__ yT,          // [C,HW,B]
    float* __restrict__ stats)       // [B*3][2]
{
    __shared__ float w_s[81];
    __shared__ float4 red[4][8][6];
    int t = threadIdx.x;
    if (t < 81) w_s[t] = wt[t];
    __syncthreads();

    int p = blockIdx.x;
    int l = (p & 7) * (NBLK_CONV / 8) + (p >> 3);   // XCD-contiguous pixels
    int bq  = t & 7;
    int pix = l * 32 + (t >> 3);

    float4 a0 = make_float4(0.f, 0.f, 0.f, 0.f), a1 = a0, a2 = a0;

    const float* x0 = xT + (size_t)bq * 4;
    const float* x1 = x0 + (size_t)HWS * 32;
    const float* x2 = x1 + (size_t)HWS * 32;

    #pragma unroll 3
    for (int k = 0; k < 9; ++k) {
        int4   ii = ti[k * HWS + pix];   // broadcast across the 8 lanes/pixel
        float4 ww = tw[k * HWS + pix];
        size_t o00 = (size_t)ii.x * 32, o01 = (size_t)ii.y * 32;
        size_t o10 = (size_t)ii.z * 32, o11 = (size_t)ii.w * 32;
        #pragma unroll
        for (int c = 0; c < 3; ++c) {
            const float* xc = (c == 0) ? x0 : ((c == 1) ? x1 : x2);
            float4 v00 = *(const float4*)(xc + o00);
            float4 v01 = *(const float4*)(xc + o01);
            float4 v10 = *(const float4*)(xc + o10);
            float4 v11 = *(const float4*)(xc + o11);
            float4 s;
            s.x = v00.x*ww.x + v01.x*ww.y + v10.x*ww.z + v11.x*ww.w;
            s.y = v00.y*ww.x + v01.y*ww.y + v10.y*ww.z + v11.y*ww.w;
            s.z = v00.z*ww.x + v01.z*ww.y + v10.z*ww.z + v11.z*ww.w;
            s.w = v00.w*ww.x + v01.w*ww.y + v10.w*ww.z + v11.w*ww.w;
            float wo0 = w_s[c * 9 + k], wo1 = w_s[27 + c * 9 + k], wo2 = w_s[54 + c * 9 + k];
            a0.x = fmaf(s.x, wo0, a0.x); a0.y = fmaf(s.y, wo0, a0.y);
            a0.z = fmaf(s.z, wo0, a0.z); a0.w = fmaf(s.w, wo0, a0.w);
            a1.x = fmaf(s.x, wo1, a1.x); a1.y = fmaf(s.y, wo1, a1.y);
            a1.z = fmaf(s.z, wo1, a1.z); a1.w = fmaf(s.w, wo1, a1.w);
            a2.x = fmaf(s.x, wo2, a2.x); a2.y = fmaf(s.y, wo2, a2.y);
            a2.z = fmaf(s.z, wo2, a2.z); a2.w = fmaf(s.w, wo2, a2.w);
        }
    }

    // coalesced float4 stores: 8 lanes x 16B = 128B contiguous per pixel group
    float* yb = yT + (size_t)pix * 32 + bq * 4;
    *(float4*)(yb)                        = a0;
    *(float4*)(yb + (size_t)HWS * 32)     = a1;
    *(float4*)(yb + (size_t)2 * HWS * 32) = a2;

    // ---- per-(b,c) sum / sumsq ----
    float4 v[6];
    v[0] = a0; v[2] = a1; v[4] = a2;
    v[1] = make_float4(a0.x*a0.x, a0.y*a0.y, a0.z*a0.z, a0.w*a0.w);
    v[3] = make_float4(a1.x*a1.x, a1.y*a1.y, a1.z*a1.z, a1.w*a1.w);
    v[5] = make_float4(a2.x*a2.x, a2.y*a2.y, a2.z*a2.z, a2.w*a2.w);
    #pragma unroll
    for (int j = 0; j < 6; ++j) {
        #pragma unroll
        for (int o = 8; o <= 32; o <<= 1) {      // sum over 8 pixel-groups/wave
            v[j].x += __shfl_xor(v[j].x, o);
            v[j].y += __shfl_xor(v[j].y, o);
            v[j].z += __shfl_xor(v[j].z, o);
            v[j].w += __shfl_xor(v[j].w, o);
        }
    }
    int lane = t & 63, wv = t >> 6;
    if (lane < 8) {
        #pragma unroll
        for (int j = 0; j < 6; ++j) red[wv][lane][j] = v[j];
    }
    __syncthreads();
    if (t < 192) {
        int bq2 = t / 24, r = t % 24, idx6 = r >> 2, comp = r & 3;
        float sum = 0.f;
        #pragma unroll
        for (int w2 = 0; w2 < 4; ++w2)
            sum += ((const float*)&red[w2][bq2][idx6])[comp];
        int b = bq2 * 4 + comp, c = idx6 >> 1, which = idx6 & 1;
        atomicAdd(&stats[(b * 3 + c) * 2 + which], sum);
    }
}

// ------- instance norm + tanh, [C,HW,B], in-place, XCD-aligned ------------
__global__ __launch_bounds__(256) void norm_t_kernel(
    float* __restrict__ y, const float* __restrict__ stats,
    const float* __restrict__ gamma, const float* __restrict__ beta)
{
    int p = blockIdx.x;
    int xcd = p & 7, i = p >> 3;            // 588 blocks per XCD slice
    int q = i * 256 + threadIdx.x;          // quad id within slice, 0..150527
    int c = q / 50176;                      // 6272 pixels * 8 quads == 50176
    int r = q - c * 50176;
    int pix = xcd * PIX_PER_XCD + (r >> 3);
    int bq = r & 7;
    float gc = gamma[c], bt = beta[c];
    float* base = y + ((size_t)(c * HWS + pix)) * 32 + bq * 4;
    float4 vv = *(float4*)base;
    #pragma unroll
    for (int j = 0; j < 4; ++j) {
        int b = bq * 4 + j;
        float s  = stats[(b * 3 + c) * 2 + 0];
        float qq = stats[(b * 3 + c) * 2 + 1];
        float mean = s * (1.f / HWS);
        float var  = fmaxf(qq * (1.f / HWS) - mean * mean, 0.f);
        float g = gc * rsqrtf(var + EPS_IN);
        ((float*)&vv)[j] = fast_tanh((((float*)&vv)[j] - mean) * g + bt);
    }
    *(float4*)base = vv;
}

// ---------------- final: norm + tanh + transpose back to [B,C,H,W] --------
__global__ __launch_bounds__(256) void norm_final_kernel(
    const float* __restrict__ y, const float* __restrict__ stats,
    const float* __restrict__ gamma, const float* __restrict__ beta,
    float* __restrict__ out)
{
    __shared__ float tile[64][33];
    int bid = blockIdx.x;
    int c = bid / (HWS / 64);
    int pix0 = (bid % (HWS / 64)) * 64;
    int t = threadIdx.x;
    int b = t & 31;
    float s  = stats[(b * 3 + c) * 2 + 0];
    float qq = stats[(b * 3 + c) * 2 + 1];
    float mean = s * (1.f / HWS);
    float var  = fmaxf(qq * (1.f / HWS) - mean * mean, 0.f);
    float inv  = rsqrtf(var + EPS_IN);
    float g = gamma[c] * inv, bt = beta[c];
    int irow = t >> 5;
    #pragma unroll
    for (int j = 0; j < 8; ++j) {
        int i = irow + j * 8;
        float v = y[((size_t)(c * HWS + pix0 + i)) * 32 + b];
        tile[i][b] = fast_tanh((v - mean) * g + bt);
    }
    __syncthreads();
    int i2 = t & 63, brow = t >> 6;
    #pragma unroll
    for (int jj = 0; jj < 8; ++jj) {
        int b2 = brow + jj * 4;
        out[((size_t)(b2 * 3 + c)) * HWS + pix0 + i2] = tile[i2][b2];
    }
}

extern "C" void kernel_launch(void* const* d_in, const int* in_sizes, int n_in,
                              void* d_out, int out_size, void* d_ws, size_t ws_size,
                              hipStream_t stream) {
    const float* x     = (const float*)d_in[0];
    const float* wt    = (const float*)d_in[1];
    const float* off   = (const float*)d_in[2];   // batch-tiled -> plane 0
    const float* gamma = (const float*)d_in[3];
    const float* beta  = (const float*)d_in[4];

    float* out  = (float*)d_out;
    float* bufA = (float*)d_ws;
    float* bufB = bufA + NELEM;
    int4*  ti   = (int4*)(bufB + NELEM);
    float4* tw  = (float4*)((char*)ti + (size_t)NTAPS * 16);
    float* stats = (float*)((char*)tw + (size_t)NTAPS * 16);
    // ws: 2*19.27MB + 2*7.2MB + 7.7KB ~= 53 MB

    zero_kernel<<<(LNUM * 192 + 255) / 256, 256, 0, stream>>>(stats, LNUM * 192);
    taps_kernel<<<NTAPS / 256, 256, 0, stream>>>(off, ti, tw);
    transpose_in_kernel<<<3 * (HWS / 64), 256, 0, stream>>>(x, bufA);

    float* cur = bufA;
    float* nxt = bufB;
    for (int it = 0; it < LNUM; ++it) {
        float* st = stats + it * 192;
        conv_t_kernel<<<NBLK_CONV, 256, 0, stream>>>(cur, ti, tw, wt, nxt, st);
        if (it < LNUM - 1)
            norm_t_kernel<<<NBLK_NORM, 256, 0, stream>>>(nxt, st, gamma, beta);
        else
            norm_final_kernel<<<3 * (HWS / 64), 256, 0, stream>>>(nxt, st, gamma, beta, out);
        float* tmp = cur; cur = nxt; nxt = tmp;
    }
}

// Round 7
// 706.464 us; speedup vs baseline: 1.6009x; 1.6009x over previous
//
#include <hip/hip_runtime.h>
#include <math.h>

#define BB 32
#define CC 3
#define HH 224
#define WW 224
#define HWS (HH*WW)            // 50176
#define NELEM (BB*CC*HWS)      // 4,816,896
#define NTAPS (9*HWS)          // 451,584
#define EPS_IN 1e-5f
#define LNUM 10

#define NBLK_CONV (BB*HWS/256)   // 6272
#define NBLK_NORM (NELEM/1024)   // 4704

__device__ __forceinline__ float fast_tanh(float z) {
    z = fminf(fmaxf(z, -15.f), 15.f);
    float e = __expf(2.f * z);
    return (e - 1.f) * __frcp_rn(e + 1.f);
}

// ---------------- zero stats ----------------
__global__ void zero_kernel(float* __restrict__ p, int n) {
    int i = blockIdx.x * 256 + threadIdx.x;
    if (i < n) p[i] = 0.f;
}

// ------- precompute expanded taps: clamped flat idx + masked weights ------
__global__ __launch_bounds__(256) void taps_kernel(
    const float* __restrict__ off,   // [18,H,W] batch-0 offset plane
    int4* __restrict__ ti, float4* __restrict__ tw)
{
    int gid = blockIdx.x * 256 + threadIdx.x;    // k*HWS + pix, grid exact
    int k = gid / HWS, pix = gid - k * HWS;
    int h = pix / WW, wc = pix - h * WW;
    int ky = k / 3, kx = k - 3 * ky;
    float dy = off[(2 * k)     * HWS + pix];
    float dx = off[(2 * k + 1) * HWS + pix];
    float py = (float)(h  + ky - 1) + dy;
    float px = (float)(wc + kx - 1) + dx;
    float y0f = floorf(py), x0f = floorf(px);
    float wy = py - y0f, wx = px - x0f;
    int iy0 = (int)y0f, ix0 = (int)x0f;
    int iy1 = iy0 + 1,  ix1 = ix0 + 1;
    float vy0 = (iy0 >= 0 && iy0 < HH) ? 1.f : 0.f;
    float vy1 = (iy1 >= 0 && iy1 < HH) ? 1.f : 0.f;
    float vx0 = (ix0 >= 0 && ix0 < WW) ? 1.f : 0.f;
    float vx1 = (ix1 >= 0 && ix1 < WW) ? 1.f : 0.f;
    int cy0 = min(max(iy0, 0), HH - 1), cy1 = min(max(iy1, 0), HH - 1);
    int cx0 = min(max(ix0, 0), WW - 1), cx1 = min(max(ix1, 0), WW - 1);
    int4 ii;
    ii.x = cy0 * WW + cx0; ii.y = cy0 * WW + cx1;
    ii.z = cy1 * WW + cx0; ii.w = cy1 * WW + cx1;
    float4 ww;
    ww.x = (1.f - wy) * (1.f - wx) * vy0 * vx0;
    ww.y = (1.f - wy) * wx         * vy0 * vx1;
    ww.z = wy         * (1.f - wx) * vy1 * vx0;
    ww.w = wy         * wx         * vy1 * vx1;
    ti[gid] = ii; tw[gid] = ww;
}

// ---------------- deformable conv (+stats), [B,C,H,W] layout ----------------
// One thread = one (b,h,w) pixel, all 3 out channels. Scalar gathers (1 VGPR
// per in-flight result -> deep MLP window), taps hoisted to registers, gather
// body fully unrolled. launch_bounds(256,4) caps VGPR at 128 (16 waves/CU,
// matching R4's achieved occupancy) while letting the scheduler keep ~30+
// loads in flight. XCD-contiguous block swizzle for L2 tap/x locality.
__global__ __launch_bounds__(256, 4) void conv_kernel(
    const float* __restrict__ x,     // [B,C,H,W]
    const int4*  __restrict__ ti,    // [9,HW]
    const float4* __restrict__ tw,   // [9,HW]
    const float* __restrict__ wt,    // [3,3,9]
    float* __restrict__ y,           // [B,C,H,W]
    float* __restrict__ stats)       // [B*3][2]
{
    __shared__ float w_s[81];
    int t = threadIdx.x;
    if (t < 81) w_s[t] = wt[t];
    __syncthreads();

    int p = blockIdx.x;
    int logical = (p & 7) * (NBLK_CONV / 8) + (p >> 3);
    int b     = logical & 31;
    int chunk = logical >> 5;            // 0..195
    int pix   = chunk * 256 + t;

    const float* xb = x + b * (CC * HWS);

    // hoist all taps into registers (72 VGPRs) — independent load stream
    int4   ii[9];
    float4 ww[9];
    #pragma unroll
    for (int k = 0; k < 9; ++k) {
        ii[k] = ti[k * HWS + pix];
        ww[k] = tw[k * HWS + pix];
    }

    float acc0 = 0.f, acc1 = 0.f, acc2 = 0.f;

    #pragma unroll
    for (int k = 0; k < 9; ++k) {
        #pragma unroll
        for (int c = 0; c < 3; ++c) {
            const float* xc = xb + c * HWS;
            float v00 = xc[ii[k].x];
            float v01 = xc[ii[k].y];
            float v10 = xc[ii[k].z];
            float v11 = xc[ii[k].w];
            float s = v00 * ww[k].x + v01 * ww[k].y + v10 * ww[k].z + v11 * ww[k].w;
            acc0 = fmaf(s, w_s[ 0 + c * 9 + k], acc0);
            acc1 = fmaf(s, w_s[27 + c * 9 + k], acc1);
            acc2 = fmaf(s, w_s[54 + c * 9 + k], acc2);
        }
    }

    float* yb = y + b * (CC * HWS) + pix;
    yb[0]       = acc0;
    yb[HWS]     = acc1;
    yb[2 * HWS] = acc2;

    // ---- per-(b,channel) sum / sumsq reduction ----
    float s0 = acc0, q0 = acc0 * acc0;
    float s1 = acc1, q1 = acc1 * acc1;
    float s2 = acc2, q2 = acc2 * acc2;
    #pragma unroll
    for (int o = 32; o > 0; o >>= 1) {
        s0 += __shfl_down(s0, o); q0 += __shfl_down(q0, o);
        s1 += __shfl_down(s1, o); q1 += __shfl_down(q1, o);
        s2 += __shfl_down(s2, o); q2 += __shfl_down(q2, o);
    }
    __shared__ float red[4][6];
    int wave = t >> 6, lane = t & 63;
    if (lane == 0) {
        red[wave][0] = s0; red[wave][1] = q0;
        red[wave][2] = s1; red[wave][3] = q1;
        red[wave][4] = s2; red[wave][5] = q2;
    }
    __syncthreads();
    if (t < 6) {
        float v = red[0][t] + red[1][t] + red[2][t] + red[3][t];
        int ch = t >> 1, which = t & 1;
        atomicAdd(&stats[(b * 3 + ch) * 2 + which], v);
    }
}

// ------------- instance norm + tanh, float4, swizzled like conv -----------
__global__ __launch_bounds__(256) void norm_kernel(
    const float* __restrict__ y, float* __restrict__ out,
    const float* __restrict__ stats,
    const float* __restrict__ gamma, const float* __restrict__ beta)
{
    int q = blockIdx.x;
    int logical = (q & 7) * (NBLK_NORM / 8) + (q >> 3);
    int pc = logical / 96;               // 1024-elem pixel chunk, 0..48
    int bc = logical - pc * 96;          // b*3+c
    int c  = bc % 3;
    float s  = stats[bc * 2 + 0];
    float qq = stats[bc * 2 + 1];
    float mean = s * (1.f / HWS);
    float var  = fmaxf(qq * (1.f / HWS) - mean * mean, 0.f);
    float g  = gamma[c] * rsqrtf(var + EPS_IN);
    float bt = beta[c];
    size_t base = (size_t)bc * HWS + pc * 1024 + threadIdx.x * 4;
    float4 v = *(const float4*)(y + base);
    v.x = fast_tanh((v.x - mean) * g + bt);
    v.y = fast_tanh((v.y - mean) * g + bt);
    v.z = fast_tanh((v.z - mean) * g + bt);
    v.w = fast_tanh((v.w - mean) * g + bt);
    *(float4*)(out + base) = v;
}

extern "C" void kernel_launch(void* const* d_in, const int* in_sizes, int n_in,
                              void* d_out, int out_size, void* d_ws, size_t ws_size,
                              hipStream_t stream) {
    const float* x     = (const float*)d_in[0];
    const float* wt    = (const float*)d_in[1];
    const float* off   = (const float*)d_in[2];   // batch-tiled -> plane 0
    const float* gamma = (const float*)d_in[3];
    const float* beta  = (const float*)d_in[4];

    float* out  = (float*)d_out;
    float* bufA = (float*)d_ws;
    float* bufB = bufA + NELEM;
    int4*  ti   = (int4*)(bufB + NELEM);
    float4* tw  = (float4*)((char*)ti + (size_t)NTAPS * 16);
    float* stats = (float*)((char*)tw + (size_t)NTAPS * 16);
    // ws: 2*19.27MB + 2*7.2MB + 7.7KB ~= 53 MB

    zero_kernel<<<(LNUM * 192 + 255) / 256, 256, 0, stream>>>(stats, LNUM * 192);
    taps_kernel<<<NTAPS / 256, 256, 0, stream>>>(off, ti, tw);

    const float* cur = x;
    for (int it = 0; it < LNUM; ++it) {
        float* conv_out = (it & 1) ? bufB : bufA;
        float* st = stats + it * 192;
        conv_kernel<<<NBLK_CONV, 256, 0, stream>>>(cur, ti, tw, wt, conv_out, st);
        float* norm_dst = (it == LNUM - 1) ? out : conv_out;
        norm_kernel<<<NBLK_NORM, 256, 0, stream>>>(conv_out, norm_dst, st, gamma, beta);
        cur = norm_dst;
        if (it == LNUM - 1) break;
    }
}